// Round 13
// baseline (195.506 us; speedup 1.0000x reference)
//
#include <hip/hip_runtime.h>

typedef __attribute__((ext_vector_type(8))) __bf16 bf16x8;
typedef __attribute__((ext_vector_type(8))) _Float16 f16x8;
typedef __attribute__((ext_vector_type(4))) float f32x4;
typedef __attribute__((ext_vector_type(8))) unsigned short u16x8;
typedef __attribute__((ext_vector_type(4))) unsigned int u32x4;

#define MFMA_BF16(a, b, c) __builtin_amdgcn_mfma_f32_16x16x32_bf16((a), (b), (c), 0, 0, 0)
#define MFMA_F16(a, b, c)  __builtin_amdgcn_mfma_f32_16x16x32_f16((a), (b), (c), 0, 0, 0)
#define LOG2E 1.44269504088896340736f
#define QSCALE 0.18033688011112042f   // 0.125 * log2(e), folded into wq at cvt

__device__ __forceinline__ float b2f(unsigned short u) {
    union { unsigned int i; float f; } v; v.i = ((unsigned int)u) << 16; return v.f;
}
__device__ __forceinline__ unsigned short f2bf(float f) {
    union { float f; unsigned int i; } v; v.f = f;
    unsigned int u = v.i;
    return (unsigned short)((u + 0x7fffu + ((u >> 16) & 1u)) >> 16);
}

// async global->LDS, 16B/lane. HW dest = wave-uniform base + lane*16 (m104).
// Swizzle is applied on the GLOBAL side so conflict-free LDS layouts coexist with it.
__device__ __forceinline__ void gl_lds16(const void* g, void* l) {
    __builtin_amdgcn_global_load_lds(
        (const __attribute__((address_space(1))) void*)g,
        (__attribute__((address_space(3))) void*)l,
        16, 0, 0);
}

// ---------------- fp32 -> bf16 conversion of all 5 inputs; wq pre-scaled ----------
__global__ __launch_bounds__(256) void cvt_all(const float* __restrict__ x,
                                               const float* __restrict__ wq,
                                               const float* __restrict__ wk,
                                               const float* __restrict__ wv,
                                               const float* __restrict__ wo,
                                               unsigned short* __restrict__ xb,
                                               unsigned short* __restrict__ wqb,
                                               unsigned short* __restrict__ wkb,
                                               unsigned short* __restrict__ wvb,
                                               unsigned short* __restrict__ wob) {
    int id = blockIdx.x * 256 + threadIdx.x;  // [0, 1M)
    const float* src; unsigned short* dst; size_t off; float scl = 1.0f;
    if (id < 524288)      { src = x;  dst = xb;  off = (size_t)id * 8; }
    else if (id < 655360) { src = wq; dst = wqb; off = (size_t)(id - 524288) * 8; scl = QSCALE; }
    else if (id < 786432) { src = wk; dst = wkb; off = (size_t)(id - 655360) * 8; }
    else if (id < 917504) { src = wv; dst = wvb; off = (size_t)(id - 786432) * 8; }
    else                  { src = wo; dst = wob; off = (size_t)(id - 917504) * 8; }
    float4 a = *(const float4*)(src + off);
    float4 b = *(const float4*)(src + off + 4);
    u16x8 o;
    o[0] = f2bf(a.x * scl); o[1] = f2bf(a.y * scl); o[2] = f2bf(a.z * scl); o[3] = f2bf(a.w * scl);
    o[4] = f2bf(b.x * scl); o[5] = f2bf(b.y * scl); o[6] = f2bf(b.z * scl); o[7] = f2bf(b.w * scl);
    *(u16x8*)(dst + off) = o;
}

// ---------------- GEMM core: C[MxN] = A[MxK]*B[NxK]^T, bf16 in, fp32 accum --------
// 128x128 tile, BK=32, K=1024 fixed, A/B row stride 1024.
// 2-PHASE SCHEDULE (catalog T3 minimum, +10% on grouped-GEMM m248v2): per K-step
// {STAGE(k+1, buf^1); compute(buf); s_waitcnt vmcnt(0) lgkmcnt(0); barrier}. The
// L2 drain of stage(k+1) overlaps ~300cy of MFMA+ds_read instead of sitting
// serially between stage and compute. Race-safe per the R6 lesson: lgkmcnt(0)
// before the barrier guarantees compute(k)'s LDS reads COMPLETED before any wave
// stages into this buffer at k+1; buf^1's last reader finished before the
// end-of-(k-1) barrier. Spill-safe: DMA uses no data-VGPRs; 256-thread kernels
// get a ~92-VGPR budget (the 64-VGPR pathology was 512-thread flash only).
// LDS chunk (r,cpos) holds source chunk cpos^((r>>1)&3) -> frag ds_read_b128 is
// 2-way (free). MODE: 0 = bf16, 1 = f32, 2 = f16, 3 = bf16 with fused RoPE.
#define GSTAGE(k0_, buf_)                                                   \
    {                                                                       \
        _Pragma("unroll")                                                   \
        for (int i = 0; i < 2; ++i) {                                       \
            int L = (w * 2 + i) * 64 + lane;                                \
            int r = L >> 2;                                                 \
            int c = (L & 3) ^ ((r >> 1) & 3);                               \
            gl_lds16(A + (size_t)(m0 + r) * 1024 + (k0_) + c * 8,           \
                     As + (buf_) * 4096 + L * 8);                           \
            gl_lds16(B + (size_t)(n0 + r) * 1024 + (k0_) + c * 8,           \
                     Bs + (buf_) * 4096 + L * 8);                           \
        }                                                                   \
    }

template <int MODE>
__device__ __forceinline__ void gemm128_bt(const unsigned short* __restrict__ A,
                                           const unsigned short* __restrict__ B,
                                           void* __restrict__ Cv,
                                           int m0, int n0, int ldc,
                                           unsigned short* As, unsigned short* Bs) {
    const int tid = threadIdx.x;
    const int w = tid >> 6, lane = tid & 63;
    const int quad = lane >> 4, l15 = lane & 15;
    const int wm = w & 1, wn = w >> 1;

    f32x4 acc[4][4];
#pragma unroll
    for (int mt = 0; mt < 4; ++mt)
#pragma unroll
        for (int nt = 0; nt < 4; ++nt) acc[mt][nt] = f32x4{0.f, 0.f, 0.f, 0.f};

    GSTAGE(0, 0)
    __asm__ volatile("s_waitcnt vmcnt(0)" ::: "memory");
    __builtin_amdgcn_s_barrier();

    int buf = 0;
    for (int k0 = 0; k0 < 1024; k0 += 32) {
        if (k0 + 32 < 1024) GSTAGE(k0 + 32, buf ^ 1)

        const unsigned short* Asb = As + buf * 4096;
        const unsigned short* Bsb = Bs + buf * 4096;
        bf16x8 af[4], bfr[4];
#pragma unroll
        for (int mt = 0; mt < 4; ++mt) {
            int row = wm * 64 + mt * 16 + l15;
            af[mt] = *(const bf16x8*)(Asb + row * 32 + (quad ^ ((row >> 1) & 3)) * 8);
        }
#pragma unroll
        for (int nt = 0; nt < 4; ++nt) {
            int row = wn * 64 + nt * 16 + l15;
            bfr[nt] = *(const bf16x8*)(Bsb + row * 32 + (quad ^ ((row >> 1) & 3)) * 8);
        }
#pragma unroll
        for (int mt = 0; mt < 4; ++mt)
#pragma unroll
            for (int nt = 0; nt < 4; ++nt)
                acc[mt][nt] = MFMA_BF16(af[mt], bfr[nt], acc[mt][nt]);

        // drain: stage(k+1) issued ~300cy ago (hidden); lgkmcnt(0) = R6 race fix
        __asm__ volatile("s_waitcnt vmcnt(0) lgkmcnt(0)" ::: "memory");
        __builtin_amdgcn_s_barrier();
        buf ^= 1;
    }

    // ---- fused RoPE (MODE 3): ch = nt*16+l15 (row-independent), pp = ch>>1 ----
    float invf[4], sgn = 0.f;
    if constexpr (MODE == 3) {
        sgn = (l15 & 1) ? 1.0f : -1.0f;   // odd lane: +p*sin ; even lane: -p*sin
#pragma unroll
        for (int nt = 0; nt < 4; ++nt)
            invf[nt] = exp2f(-0.41524101186092029f * (float)((nt * 16 + l15) >> 1));
    }

#pragma unroll
    for (int mt = 0; mt < 4; ++mt) {
        int grow = m0 + wm * 64 + mt * 16 + quad * 4;
#pragma unroll
        for (int nt = 0; nt < 4; ++nt) {
            int gcol = n0 + wn * 64 + nt * 16 + l15;
#pragma unroll
            for (int r = 0; r < 4; ++r) {
                float val = acc[mt][nt][r];
                size_t idx = (size_t)(grow + r) * ldc + gcol;
                if constexpr (MODE == 0) {
                    ((unsigned short*)Cv)[idx] = f2bf(val);
                } else if constexpr (MODE == 1) {
                    ((float*)Cv)[idx] = val;
                } else if constexpr (MODE == 2) {
                    _Float16 hv = (_Float16)val;
                    ((unsigned short*)Cv)[idx] = __builtin_bit_cast(unsigned short, hv);
                } else {
                    float p = __shfl_xor(val, 1);              // pair partner channel
                    float pos = (float)((grow + r) & 2047);    // seq position
                    float ang = pos * invf[nt];
                    float out = val * __cosf(ang) + sgn * p * __sinf(ang);
                    ((unsigned short*)Cv)[idx] = f2bf(out);
                }
            }
        }
    }
}
#undef GSTAGE

// Q/K: bf16 + fused RoPE (ldc 1024). V: C = Wv * X^T = V^T[ch][token] f16 (ldc 4096).
__global__ __launch_bounds__(256) void gemm_qkv(const unsigned short* __restrict__ X,
                                                const unsigned short* __restrict__ Wq,
                                                const unsigned short* __restrict__ Wk,
                                                const unsigned short* __restrict__ Wv,
                                                unsigned short* __restrict__ Qo,
                                                unsigned short* __restrict__ Ko,
                                                unsigned short* __restrict__ Vt) {
    __shared__ unsigned short As[2 * 128 * 32];
    __shared__ unsigned short Bs[2 * 128 * 32];
    int y = blockIdx.y;
    if (y < 16) {
        int sel = y >> 3;
        int m0 = blockIdx.x * 128;         // tokens
        int n0 = (y & 7) * 128;            // channels
        const unsigned short* B = sel ? Wk : Wq;
        unsigned short* C = sel ? Ko : Qo;
        gemm128_bt<3>(X, B, C, m0, n0, 1024, As, Bs);
    } else {
        int m0 = (y & 7) * 128;            // channels
        int n0 = blockIdx.x * 128;         // tokens
        gemm128_bt<2>(Wv, X, Vt, m0, n0, 4096, As, Bs);
    }
}

__global__ __launch_bounds__(256) void gemm_out(const unsigned short* __restrict__ A,
                                                const unsigned short* __restrict__ Wo,
                                                float* __restrict__ C) {
    __shared__ unsigned short As[2 * 128 * 32];
    __shared__ unsigned short Bs[2 * 128 * 32];
    gemm128_bt<1>(A, Wo, C, blockIdx.x * 128, blockIdx.y * 128, 1024, As, Bs);
}

// ---------------- Flash attention: key-split 8-wave blocks (R12 champion) ---------
// 512 blocks x 512 threads -> 2 blocks/CU, 16 waves/CU (4/SIMD). Waves 0-3 (g=0)
// process keys it*128..+63, waves 4-7 (g=1) keys +64..127; partial O/rowsum are
// additive (no max tracking) -> one LDS reduction at block end.
// Staging: {sync; stage 32KB; sync; compute} -- the empirically best schedule
// (R5/R12); every restructure regressed (R2/R3 counted-vmcnt ~55-59, R7/R8 2-phase
// ~58 w/ spills). FBODY: ds_swizzle PV -- the ONLY spill-free FBODY at the
// backend's immovable 64-VGPR budget for 512-thread kernels (nat-PV variants
// spill: WRITE_SIZE 31MB in R6/R7/R8/R11; this one: 10MB). Red reduction layout
// [vec][256 lanes][4] (16B lane stride, conflict-free) -- verified win in R12.
// Swapped QK (mfma(K,Q)) keeps P lane-local; PV A-operand rebuilt quad-blocked
// with two ds_swizzle xor-16 per 32-key half; V read as conflict-free b128 chunks.
// Rowsum via ones-MFMA on pre-exchange P (permutation-invariant).
#define FBODY(KBASE, MASKED)                                                            \
    {                                                                                   \
        bf16x8 kf[4][2];                                                                \
        _Pragma("unroll")                                                               \
        for (int nt = 0; nt < 4; ++nt) {                                                \
            int row = nt * 16 + l15;                                                    \
            const unsigned short* kp = Ksb + row * 64;                                  \
            int swk = row & 7;                                                          \
            kf[nt][0] = *(const bf16x8*)(kp + (quad ^ swk) * 8);                        \
            kf[nt][1] = *(const bf16x8*)(kp + ((quad ^ 4) ^ swk) * 8);                  \
        }                                                                               \
        f16x8 pa[2][2];                                                                 \
        _Pragma("unroll")                                                               \
        for (int mt = 0; mt < 2; ++mt) {                                                \
            f32x4 sc[4];                                                                \
            _Pragma("unroll")                                                           \
            for (int nt = 0; nt < 4; ++nt) {                                            \
                f32x4 z = f32x4{0.f, 0.f, 0.f, 0.f};                                    \
                z = MFMA_BF16(kf[nt][0], qf[mt][0], z);                                 \
                sc[nt] = MFMA_BF16(kf[nt][1], qf[mt][1], z);                            \
            }                                                                           \
            int qpos = qposw + mt * 16 + l15;                                           \
            unsigned pk[8];                                                             \
            _Pragma("unroll")                                                           \
            for (int nt = 0; nt < 4; ++nt) {                                            \
                float e[4];                                                             \
                _Pragma("unroll")                                                       \
                for (int r_ = 0; r_ < 4; ++r_) {                                        \
                    float ev = exp2f(sc[nt][r_]);                                       \
                    if (MASKED) {                                                       \
                        int kpos = (KBASE) + nt * 16 + quad * 4 + r_;                   \
                        ev = (kpos > qpos) ? 0.f : ev;                                  \
                    }                                                                   \
                    e[r_] = ev;                                                         \
                }                                                                       \
                pk[nt * 2 + 0] = __builtin_bit_cast(unsigned,                           \
                                     __builtin_amdgcn_cvt_pkrtz(e[0], e[1]));           \
                pk[nt * 2 + 1] = __builtin_bit_cast(unsigned,                           \
                                     __builtin_amdgcn_cvt_pkrtz(e[2], e[3]));           \
            }                                                                           \
            u32x4 rs0 = u32x4{pk[0], pk[1], pk[2], pk[3]};                              \
            u32x4 rs1 = u32x4{pk[4], pk[5], pk[6], pk[7]};                              \
            lacc[mt] = MFMA_F16(__builtin_bit_cast(f16x8, rs0), ones, lacc[mt]);        \
            lacc[mt] = MFMA_F16(__builtin_bit_cast(f16x8, rs1), ones, lacc[mt]);        \
            int b0 = quad & 1;                                                          \
            unsigned y0 = (unsigned)__builtin_amdgcn_ds_swizzle(                        \
                              (int)(b0 ? pk[0] : pk[2]), 0x401F);                       \
            unsigned y1 = (unsigned)__builtin_amdgcn_ds_swizzle(                        \
                              (int)(b0 ? pk[1] : pk[3]), 0x401F);                       \
            unsigned y2 = (unsigned)__builtin_amdgcn_ds_swizzle(                        \
                              (int)(b0 ? pk[4] : pk[6]), 0x401F);                       \
            unsigned y3 = (unsigned)__builtin_amdgcn_ds_swizzle(                        \
                              (int)(b0 ? pk[5] : pk[7]), 0x401F);                       \
            u32x4 t0 = b0 ? u32x4{y0, y1, pk[2], pk[3]}                                 \
                          : u32x4{pk[0], pk[1], y0, y1};                                \
            u32x4 t1 = b0 ? u32x4{y2, y3, pk[6], pk[7]}                                 \
                          : u32x4{pk[4], pk[5], y2, y3};                                \
            pa[mt][0] = __builtin_bit_cast(f16x8, t0);                                  \
            pa[mt][1] = __builtin_bit_cast(f16x8, t1);                                  \
        }                                                                               \
        _Pragma("unroll")                                                               \
        for (int nt = 0; nt < 4; ++nt) {                                                \
            int rowd = nt * 16 + l15;                                                   \
            const unsigned short* vp = Vsb + rowd * 64;                                 \
            int sl0 = pi4 ^ (rowd & 7);                                                 \
            f16x8 v0 = *(const f16x8*)(vp + sl0 * 8);                                   \
            f16x8 v1 = *(const f16x8*)(vp + (sl0 ^ 4) * 8);                             \
            accO[0][nt] = MFMA_F16(pa[0][0], v0, accO[0][nt]);                          \
            accO[1][nt] = MFMA_F16(pa[1][0], v0, accO[1][nt]);                          \
            accO[0][nt] = MFMA_F16(pa[0][1], v1, accO[0][nt]);                          \
            accO[1][nt] = MFMA_F16(pa[1][1], v1, accO[1][nt]);                          \
        }                                                                               \
    }

__global__ __launch_bounds__(512, 4) void flash_attn(const unsigned short* __restrict__ Q,
                                                     const unsigned short* __restrict__ Kb,
                                                     const unsigned short* __restrict__ Vt,
                                                     unsigned short* __restrict__ O) {
    int id = blockIdx.x;            // 512 blocks
    int xcd = id & 7;
    int s  = id >> 3;               // 0..63
    int rr = s & 3;
    int t  = s >> 2;                // 0..15
    int qt = (t < 8) ? t : 23 - t;  // id and id+256 share a CU -> iteration sum = 17
    int bh = xcd + 8 * rr;          // 4 bh per XCD -> K/V/Q slices L2-resident
    int b = bh >> 4, h = bh & 15;
    int tid = threadIdx.x;
    int wv8 = tid >> 6;             // 0..7
    int g = wv8 >> 2;               // key-group (0: keys +0..63, 1: keys +64..127)
    int w = wv8 & 3;                // q-wave within group (32 rows each)
    int lane = tid & 63;
    int quad = lane >> 4, l15 = lane & 15;
    int pi4 = ((quad & 1) << 1) | (quad >> 1);   // V chunk owned by this quad

    // 40KB: K/V staging (32KB) during loop; [vec][256][4] reduction after
    __shared__ __align__(16) float Red[10240];
    unsigned short* Ks = (unsigned short*)Red;        // [2 groups][64 rows][64]
    unsigned short* Vs = Ks + 8192;                   // [2 groups][64 d-rows][64]

    // staging: 512 threads, 1 chunk of 16B per tile each (4 tiles = 32KB/iter).
    // chunk L=tid: row r=L>>3, lds chunk-col cpos=L&7 holds src col cpos^(r&7)
    int r = tid >> 3, c = (tid & 7) ^ (r & 7);
    const unsigned short* KgT = Kb + (size_t)(b * 2048 + r) * 1024 + h * 64 + c * 8;
    const unsigned short* VgT = Vt + (size_t)(h * 64 + r) * 4096 + b * 2048 + c * 8;

    int qrow0 = b * 2048 + qt * 128 + w * 32;
    int qposw = qt * 128 + w * 32;
    int nit = qt + 1;

    bf16x8 qf[2][2];
#pragma unroll
    for (int mt = 0; mt < 2; ++mt) {
        const unsigned short* qp =
            Q + (size_t)(qrow0 + mt * 16 + l15) * 1024 + h * 64 + quad * 8;
        qf[mt][0] = *(const bf16x8*)qp;
        qf[mt][1] = *(const bf16x8*)(qp + 32);
    }

    f16x8 ones;
#pragma unroll
    for (int tt = 0; tt < 8; ++tt) ones[tt] = (_Float16)1.0f;

    f32x4 accO[2][4];
    f32x4 lacc[2];
#pragma unroll
    for (int mt = 0; mt < 2; ++mt) {
        lacc[mt] = f32x4{0.f, 0.f, 0.f, 0.f};
#pragma unroll
        for (int nt = 0; nt < 4; ++nt) accO[mt][nt] = f32x4{0.f, 0.f, 0.f, 0.f};
    }

    for (int it = 0; it < nit; ++it) {
        __syncthreads();                    // previous compute done (WAR for staging)
        {
            size_t ko = (size_t)(it * 128) * 1024;
            int vo = it * 128;
            gl_lds16(KgT + ko, Ks + tid * 8);                      // keys +0..63
            gl_lds16(KgT + ko + 64 * 1024, Ks + 4096 + tid * 8);   // keys +64..127
            gl_lds16(VgT + vo, Vs + tid * 8);
            gl_lds16(VgT + vo + 64, Vs + 4096 + tid * 8);
        }
        __syncthreads();                    // vmcnt drain + visibility
        const unsigned short* Ksb = Ks + g * 4096;
        const unsigned short* Vsb = Vs + g * 4096;
        int kbase = it * 128 + g * 64;
        if (it < nit - 1) {
            FBODY(kbase, 0)
        } else {
            FBODY(kbase, 1)                 // diagonal 128 keys: both groups masked
        }
    }

    // ---- cross-group reduction: [vec][256 lanes][4] layout, 16B lane stride ----
    __syncthreads();                        // last FBODY reads done; LDS reusable
    if (g == 1) {
        float* dst = Red + (size_t)(w * 64 + lane) * 4;
#pragma unroll
        for (int mt = 0; mt < 2; ++mt)
#pragma unroll
            for (int nt = 0; nt < 4; ++nt)
                *(f32x4*)(dst + (mt * 4 + nt) * 1024) = accO[mt][nt];
        *(f32x4*)(dst + 8 * 1024) = lacc[0];
        *(f32x4*)(dst + 9 * 1024) = lacc[1];
    }
    __syncthreads();
    if (g == 0) {
        const float* src = Red + (size_t)(w * 64 + lane) * 4;
#pragma unroll
        for (int mt = 0; mt < 2; ++mt)
#pragma unroll
            for (int nt = 0; nt < 4; ++nt)
                accO[mt][nt] += *(const f32x4*)(src + (mt * 4 + nt) * 1024);
        lacc[0] += *(const f32x4*)(src + 8 * 1024);
        lacc[1] += *(const f32x4*)(src + 9 * 1024);

        // epilogue: accO lane layout q = mt*16 + quad*4 + r
#pragma unroll
        for (int mt = 0; mt < 2; ++mt) {
            float inv[4];
#pragma unroll
            for (int r_ = 0; r_ < 4; ++r_) inv[r_] = 1.0f / lacc[mt][r_];
#pragma unroll
            for (int nt = 0; nt < 4; ++nt)
#pragma unroll
                for (int r_ = 0; r_ < 4; ++r_)
                    O[(size_t)(qrow0 + mt * 16 + quad * 4 + r_) * 1024 +
                      h * 64 + nt * 16 + l15] = f2bf(accO[mt][nt][r_] * inv[r_]);
        }
    }
}

extern "C" void kernel_launch(void* const* d_in, const int* in_sizes, int n_in,
                              void* d_out, int out_size, void* d_ws, size_t ws_size,
                              hipStream_t stream) {
    (void)in_sizes; (void)n_in; (void)out_size; (void)ws_size;
    const float* x  = (const float*)d_in[0];
    const float* wq = (const float*)d_in[1];
    const float* wk = (const float*)d_in[2];
    const float* wv = (const float*)d_in[3];
    const float* wo = (const float*)d_in[4];
    float* out = (float*)d_out;

    const size_t T = (size_t)4096 * 1024;
    const size_t W = (size_t)1024 * 1024;
    unsigned short* Q   = (unsigned short*)d_ws;
    unsigned short* K   = Q + T;
    unsigned short* Vt  = K + T;      // f16 [ch][token], ldc 4096
    unsigned short* xb  = Vt + T;
    unsigned short* AO  = xb;         // alias: xb dead after gemm_qkv, AO written by flash
    unsigned short* wqb = xb + T;
    unsigned short* wkb = wqb + W;
    unsigned short* wvb = wkb + W;
    unsigned short* wob = wvb + W;
    // ws use: 4*8MB + 4*2MB = 40MB

    cvt_all  <<<dim3(4096),   256, 0, stream>>>(x, wq, wk, wv, wo, xb, wqb, wkb, wvb, wob);
    gemm_qkv <<<dim3(32, 24), 256, 0, stream>>>(xb, wqb, wkb, wvb, Q, K, Vt);
    flash_attn<<<dim3(512),   512, 0, stream>>>(Q, K, Vt, AO);
    gemm_out <<<dim3(32, 8),  256, 0, stream>>>(AO, wob, out);
}

// Round 14
// 177.681 us; speedup vs baseline: 1.1003x; 1.1003x over previous
//
#include <hip/hip_runtime.h>

typedef __attribute__((ext_vector_type(8))) __bf16 bf16x8;
typedef __attribute__((ext_vector_type(8))) _Float16 f16x8;
typedef __attribute__((ext_vector_type(4))) float f32x4;
typedef __attribute__((ext_vector_type(8))) unsigned short u16x8;
typedef __attribute__((ext_vector_type(4))) unsigned int u32x4;

#define MFMA_BF16(a, b, c) __builtin_amdgcn_mfma_f32_16x16x32_bf16((a), (b), (c), 0, 0, 0)
#define MFMA_F16(a, b, c)  __builtin_amdgcn_mfma_f32_16x16x32_f16((a), (b), (c), 0, 0, 0)
#define LOG2E 1.44269504088896340736f
#define QSCALE 0.18033688011112042f   // 0.125 * log2(e), folded into wq at cvt

__device__ __forceinline__ float b2f(unsigned short u) {
    union { unsigned int i; float f; } v; v.i = ((unsigned int)u) << 16; return v.f;
}
__device__ __forceinline__ unsigned short f2bf(float f) {
    union { float f; unsigned int i; } v; v.f = f;
    unsigned int u = v.i;
    return (unsigned short)((u + 0x7fffu + ((u >> 16) & 1u)) >> 16);
}

// async global->LDS, 16B/lane. HW dest = wave-uniform base + lane*16 (m104).
// Swizzle is applied on the GLOBAL side so conflict-free LDS layouts coexist with it.
__device__ __forceinline__ void gl_lds16(const void* g, void* l) {
    __builtin_amdgcn_global_load_lds(
        (const __attribute__((address_space(1))) void*)g,
        (__attribute__((address_space(3))) void*)l,
        16, 0, 0);
}

// ---------------- fp32 -> bf16 conversion of all 5 inputs; wq pre-scaled ----------
__global__ __launch_bounds__(256) void cvt_all(const float* __restrict__ x,
                                               const float* __restrict__ wq,
                                               const float* __restrict__ wk,
                                               const float* __restrict__ wv,
                                               const float* __restrict__ wo,
                                               unsigned short* __restrict__ xb,
                                               unsigned short* __restrict__ wqb,
                                               unsigned short* __restrict__ wkb,
                                               unsigned short* __restrict__ wvb,
                                               unsigned short* __restrict__ wob) {
    int id = blockIdx.x * 256 + threadIdx.x;  // [0, 1M)
    const float* src; unsigned short* dst; size_t off; float scl = 1.0f;
    if (id < 524288)      { src = x;  dst = xb;  off = (size_t)id * 8; }
    else if (id < 655360) { src = wq; dst = wqb; off = (size_t)(id - 524288) * 8; scl = QSCALE; }
    else if (id < 786432) { src = wk; dst = wkb; off = (size_t)(id - 655360) * 8; }
    else if (id < 917504) { src = wv; dst = wvb; off = (size_t)(id - 786432) * 8; }
    else                  { src = wo; dst = wob; off = (size_t)(id - 917504) * 8; }
    float4 a = *(const float4*)(src + off);
    float4 b = *(const float4*)(src + off + 4);
    u16x8 o;
    o[0] = f2bf(a.x * scl); o[1] = f2bf(a.y * scl); o[2] = f2bf(a.z * scl); o[3] = f2bf(a.w * scl);
    o[4] = f2bf(b.x * scl); o[5] = f2bf(b.y * scl); o[6] = f2bf(b.z * scl); o[7] = f2bf(b.w * scl);
    *(u16x8*)(dst + off) = o;
}

// ---------------- GEMM core: C[MxN] = A[MxK]*B[NxK]^T, bf16 in, fp32 accum --------
// 128x128 tile, BK=32, K=1024 fixed, A/B row stride 1024 (R5/R12-exact champion:
// empirically best of {this, BK=64, BN=64, 2-phase dbuf} -- R9/R10/R13 regressed).
// LDS chunk (r,cpos) holds source chunk cpos^((r>>1)&3) -> frag ds_read_b128 is
// 2-way (free). MODE: 0 = bf16, 1 = f32, 2 = f16, 3 = bf16 with fused RoPE.
template <int MODE>
__device__ __forceinline__ void gemm128_bt(const unsigned short* __restrict__ A,
                                           const unsigned short* __restrict__ B,
                                           void* __restrict__ Cv,
                                           int m0, int n0, int ldc,
                                           unsigned short* As, unsigned short* Bs) {
    const int tid = threadIdx.x;
    const int w = tid >> 6, lane = tid & 63;
    const int quad = lane >> 4, l15 = lane & 15;
    const int wm = w & 1, wn = w >> 1;

    f32x4 acc[4][4];
#pragma unroll
    for (int mt = 0; mt < 4; ++mt)
#pragma unroll
        for (int nt = 0; nt < 4; ++nt) acc[mt][nt] = f32x4{0.f, 0.f, 0.f, 0.f};

    for (int k0 = 0; k0 < 1024; k0 += 32) {
        __syncthreads();
#pragma unroll
        for (int i = 0; i < 2; ++i) {
            int L = (w * 2 + i) * 64 + lane;      // chunk index in tile
            int r = L >> 2;
            int c = (L & 3) ^ ((r >> 1) & 3);     // swizzled source chunk
            gl_lds16(A + (size_t)(m0 + r) * 1024 + k0 + c * 8, As + L * 8);
            gl_lds16(B + (size_t)(n0 + r) * 1024 + k0 + c * 8, Bs + L * 8);
        }
        __syncthreads();

        bf16x8 af[4], bfr[4];
#pragma unroll
        for (int mt = 0; mt < 4; ++mt) {
            int row = wm * 64 + mt * 16 + l15;
            af[mt] = *(const bf16x8*)(As + row * 32 + (quad ^ ((row >> 1) & 3)) * 8);
        }
#pragma unroll
        for (int nt = 0; nt < 4; ++nt) {
            int row = wn * 64 + nt * 16 + l15;
            bfr[nt] = *(const bf16x8*)(Bs + row * 32 + (quad ^ ((row >> 1) & 3)) * 8);
        }
#pragma unroll
        for (int mt = 0; mt < 4; ++mt)
#pragma unroll
            for (int nt = 0; nt < 4; ++nt)
                acc[mt][nt] = MFMA_BF16(af[mt], bfr[nt], acc[mt][nt]);
    }

    // ---- fused RoPE (MODE 3): ch = nt*16+l15 (row-independent), pp = ch>>1 ----
    float invf[4], sgn = 0.f;
    if constexpr (MODE == 3) {
        sgn = (l15 & 1) ? 1.0f : -1.0f;   // odd lane: +p*sin ; even lane: -p*sin
#pragma unroll
        for (int nt = 0; nt < 4; ++nt)
            invf[nt] = exp2f(-0.41524101186092029f * (float)((nt * 16 + l15) >> 1));
    }

#pragma unroll
    for (int mt = 0; mt < 4; ++mt) {
        int grow = m0 + wm * 64 + mt * 16 + quad * 4;
#pragma unroll
        for (int nt = 0; nt < 4; ++nt) {
            int gcol = n0 + wn * 64 + nt * 16 + l15;
#pragma unroll
            for (int r = 0; r < 4; ++r) {
                float val = acc[mt][nt][r];
                size_t idx = (size_t)(grow + r) * ldc + gcol;
                if constexpr (MODE == 0) {
                    ((unsigned short*)Cv)[idx] = f2bf(val);
                } else if constexpr (MODE == 1) {
                    ((float*)Cv)[idx] = val;
                } else if constexpr (MODE == 2) {
                    _Float16 hv = (_Float16)val;
                    ((unsigned short*)Cv)[idx] = __builtin_bit_cast(unsigned short, hv);
                } else {
                    float p = __shfl_xor(val, 1);              // pair partner channel
                    float pos = (float)((grow + r) & 2047);    // seq position
                    float ang = pos * invf[nt];
                    float out = val * __cosf(ang) + sgn * p * __sinf(ang);
                    ((unsigned short*)Cv)[idx] = f2bf(out);
                }
            }
        }
    }
}

// Q/K: bf16 + fused RoPE (ldc 1024). V: C = Wv * X^T = V^T[ch][token] f16 (ldc 4096).
__global__ __launch_bounds__(256) void gemm_qkv(const unsigned short* __restrict__ X,
                                                const unsigned short* __restrict__ Wq,
                                                const unsigned short* __restrict__ Wk,
                                                const unsigned short* __restrict__ Wv,
                                                unsigned short* __restrict__ Qo,
                                                unsigned short* __restrict__ Ko,
                                                unsigned short* __restrict__ Vt) {
    __shared__ unsigned short As[128 * 32];
    __shared__ unsigned short Bs[128 * 32];
    int y = blockIdx.y;
    if (y < 16) {
        int sel = y >> 3;
        int m0 = blockIdx.x * 128;         // tokens
        int n0 = (y & 7) * 128;            // channels
        const unsigned short* B = sel ? Wk : Wq;
        unsigned short* C = sel ? Ko : Qo;
        gemm128_bt<3>(X, B, C, m0, n0, 1024, As, Bs);
    } else {
        int m0 = (y & 7) * 128;            // channels
        int n0 = blockIdx.x * 128;         // tokens
        gemm128_bt<2>(Wv, X, Vt, m0, n0, 4096, As, Bs);
    }
}

__global__ __launch_bounds__(256) void gemm_out(const unsigned short* __restrict__ A,
                                                const unsigned short* __restrict__ Wo,
                                                float* __restrict__ C) {
    __shared__ unsigned short As[128 * 32];
    __shared__ unsigned short Bs[128 * 32];
    gemm128_bt<1>(A, Wo, C, blockIdx.x * 128, blockIdx.y * 128, 1024, As, Bs);
}

// ---------------- Flash attention: key-split 8-wave blocks (R12 champion) ---------
// 512 blocks x 512 threads -> 2 blocks/CU, 16 waves/CU (4/SIMD). Waves 0-3 (g=0)
// process keys it*128..+63, waves 4-7 (g=1) keys +64..127; partial O/rowsum are
// additive (no max tracking) -> one LDS reduction at block end.
// Staging: {sync; stage 32KB; sync; compute} -- the empirically best schedule
// (R5/R12); every restructure regressed (R2/R3 counted-vmcnt ~55-59, R7/R8 2-phase
// ~58 w/ spills). FBODY: ds_swizzle PV -- the ONLY spill-free FBODY at the
// backend's immovable 64-VGPR budget for 512-thread kernels (nat-PV variants
// spill: WRITE_SIZE 31MB in R6/R7/R8/R11; this one: 10MB). Red reduction layout
// [vec][256 lanes][4] (16B lane stride, conflict-free) -- verified win in R12
// (conflicts 2.54M -> 1.11M, flash 46.6 -> 45.7us).
// Swapped QK (mfma(K,Q)) keeps P lane-local; PV A-operand rebuilt quad-blocked
// with two ds_swizzle xor-16 per 32-key half; V read as conflict-free b128 chunks.
// Rowsum via ones-MFMA on pre-exchange P (permutation-invariant).
#define FBODY(KBASE, MASKED)                                                            \
    {                                                                                   \
        bf16x8 kf[4][2];                                                                \
        _Pragma("unroll")                                                               \
        for (int nt = 0; nt < 4; ++nt) {                                                \
            int row = nt * 16 + l15;                                                    \
            const unsigned short* kp = Ksb + row * 64;                                  \
            int swk = row & 7;                                                          \
            kf[nt][0] = *(const bf16x8*)(kp + (quad ^ swk) * 8);                        \
            kf[nt][1] = *(const bf16x8*)(kp + ((quad ^ 4) ^ swk) * 8);                  \
        }                                                                               \
        f16x8 pa[2][2];                                                                 \
        _Pragma("unroll")                                                               \
        for (int mt = 0; mt < 2; ++mt) {                                                \
            f32x4 sc[4];                                                                \
            _Pragma("unroll")                                                           \
            for (int nt = 0; nt < 4; ++nt) {                                            \
                f32x4 z = f32x4{0.f, 0.f, 0.f, 0.f};                                    \
                z = MFMA_BF16(kf[nt][0], qf[mt][0], z);                                 \
                sc[nt] = MFMA_BF16(kf[nt][1], qf[mt][1], z);                            \
            }                                                                           \
            int qpos = qposw + mt * 16 + l15;                                           \
            unsigned pk[8];                                                             \
            _Pragma("unroll")                                                           \
            for (int nt = 0; nt < 4; ++nt) {                                            \
                float e[4];                                                             \
                _Pragma("unroll")                                                       \
                for (int r_ = 0; r_ < 4; ++r_) {                                        \
                    float ev = exp2f(sc[nt][r_]);                                       \
                    if (MASKED) {                                                       \
                        int kpos = (KBASE) + nt * 16 + quad * 4 + r_;                   \
                        ev = (kpos > qpos) ? 0.f : ev;                                  \
                    }                                                                   \
                    e[r_] = ev;                                                         \
                }                                                                       \
                pk[nt * 2 + 0] = __builtin_bit_cast(unsigned,                           \
                                     __builtin_amdgcn_cvt_pkrtz(e[0], e[1]));           \
                pk[nt * 2 + 1] = __builtin_bit_cast(unsigned,                           \
                                     __builtin_amdgcn_cvt_pkrtz(e[2], e[3]));           \
            }                                                                           \
            u32x4 rs0 = u32x4{pk[0], pk[1], pk[2], pk[3]};                              \
            u32x4 rs1 = u32x4{pk[4], pk[5], pk[6], pk[7]};                              \
            lacc[mt] = MFMA_F16(__builtin_bit_cast(f16x8, rs0), ones, lacc[mt]);        \
            lacc[mt] = MFMA_F16(__builtin_bit_cast(f16x8, rs1), ones, lacc[mt]);        \
            int b0 = quad & 1;                                                          \
            unsigned y0 = (unsigned)__builtin_amdgcn_ds_swizzle(                        \
                              (int)(b0 ? pk[0] : pk[2]), 0x401F);                       \
            unsigned y1 = (unsigned)__builtin_amdgcn_ds_swizzle(                        \
                              (int)(b0 ? pk[1] : pk[3]), 0x401F);                       \
            unsigned y2 = (unsigned)__builtin_amdgcn_ds_swizzle(                        \
                              (int)(b0 ? pk[4] : pk[6]), 0x401F);                       \
            unsigned y3 = (unsigned)__builtin_amdgcn_ds_swizzle(                        \
                              (int)(b0 ? pk[5] : pk[7]), 0x401F);                       \
            u32x4 t0 = b0 ? u32x4{y0, y1, pk[2], pk[3]}                                 \
                          : u32x4{pk[0], pk[1], y0, y1};                                \
            u32x4 t1 = b0 ? u32x4{y2, y3, pk[6], pk[7]}                                 \
                          : u32x4{pk[4], pk[5], y2, y3};                                \
            pa[mt][0] = __builtin_bit_cast(f16x8, t0);                                  \
            pa[mt][1] = __builtin_bit_cast(f16x8, t1);                                  \
        }                                                                               \
        _Pragma("unroll")                                                               \
        for (int nt = 0; nt < 4; ++nt) {                                                \
            int rowd = nt * 16 + l15;                                                   \
            const unsigned short* vp = Vsb + rowd * 64;                                 \
            int sl0 = pi4 ^ (rowd & 7);                                                 \
            f16x8 v0 = *(const f16x8*)(vp + sl0 * 8);                                   \
            f16x8 v1 = *(const f16x8*)(vp + (sl0 ^ 4) * 8);                             \
            accO[0][nt] = MFMA_F16(pa[0][0], v0, accO[0][nt]);                          \
            accO[1][nt] = MFMA_F16(pa[1][0], v0, accO[1][nt]);                          \
            accO[0][nt] = MFMA_F16(pa[0][1], v1, accO[0][nt]);                          \
            accO[1][nt] = MFMA_F16(pa[1][1], v1, accO[1][nt]);                          \
        }                                                                               \
    }

__global__ __launch_bounds__(512, 4) void flash_attn(const unsigned short* __restrict__ Q,
                                                     const unsigned short* __restrict__ Kb,
                                                     const unsigned short* __restrict__ Vt,
                                                     unsigned short* __restrict__ O) {
    int id = blockIdx.x;            // 512 blocks
    int xcd = id & 7;
    int s  = id >> 3;               // 0..63
    int rr = s & 3;
    int t  = s >> 2;                // 0..15
    int qt = (t < 8) ? t : 23 - t;  // id and id+256 share a CU -> iteration sum = 17
    int bh = xcd + 8 * rr;          // 4 bh per XCD -> K/V/Q slices L2-resident
    int b = bh >> 4, h = bh & 15;
    int tid = threadIdx.x;
    int wv8 = tid >> 6;             // 0..7
    int g = wv8 >> 2;               // key-group (0: keys +0..63, 1: keys +64..127)
    int w = wv8 & 3;                // q-wave within group (32 rows each)
    int lane = tid & 63;
    int quad = lane >> 4, l15 = lane & 15;
    int pi4 = ((quad & 1) << 1) | (quad >> 1);   // V chunk owned by this quad

    // 40KB: K/V staging (32KB) during loop; [vec][256][4] reduction after
    __shared__ __align__(16) float Red[10240];
    unsigned short* Ks = (unsigned short*)Red;        // [2 groups][64 rows][64]
    unsigned short* Vs = Ks + 8192;                   // [2 groups][64 d-rows][64]

    // staging: 512 threads, 1 chunk of 16B per tile each (4 tiles = 32KB/iter).
    // chunk L=tid: row r=L>>3, lds chunk-col cpos=L&7 holds src col cpos^(r&7)
    int r = tid >> 3, c = (tid & 7) ^ (r & 7);
    const unsigned short* KgT = Kb + (size_t)(b * 2048 + r) * 1024 + h * 64 + c * 8;
    const unsigned short* VgT = Vt + (size_t)(h * 64 + r) * 4096 + b * 2048 + c * 8;

    int qrow0 = b * 2048 + qt * 128 + w * 32;
    int qposw = qt * 128 + w * 32;
    int nit = qt + 1;

    bf16x8 qf[2][2];
#pragma unroll
    for (int mt = 0; mt < 2; ++mt) {
        const unsigned short* qp =
            Q + (size_t)(qrow0 + mt * 16 + l15) * 1024 + h * 64 + quad * 8;
        qf[mt][0] = *(const bf16x8*)qp;
        qf[mt][1] = *(const bf16x8*)(qp + 32);
    }

    f16x8 ones;
#pragma unroll
    for (int tt = 0; tt < 8; ++tt) ones[tt] = (_Float16)1.0f;

    f32x4 accO[2][4];
    f32x4 lacc[2];
#pragma unroll
    for (int mt = 0; mt < 2; ++mt) {
        lacc[mt] = f32x4{0.f, 0.f, 0.f, 0.f};
#pragma unroll
        for (int nt = 0; nt < 4; ++nt) accO[mt][nt] = f32x4{0.f, 0.f, 0.f, 0.f};
    }

    for (int it = 0; it < nit; ++it) {
        __syncthreads();                    // previous compute done (WAR for staging)
        {
            size_t ko = (size_t)(it * 128) * 1024;
            int vo = it * 128;
            gl_lds16(KgT + ko, Ks + tid * 8);                      // keys +0..63
            gl_lds16(KgT + ko + 64 * 1024, Ks + 4096 + tid * 8);   // keys +64..127
            gl_lds16(VgT + vo, Vs + tid * 8);
            gl_lds16(VgT + vo + 64, Vs + 4096 + tid * 8);
        }
        __syncthreads();                    // vmcnt drain + visibility
        const unsigned short* Ksb = Ks + g * 4096;
        const unsigned short* Vsb = Vs + g * 4096;
        int kbase = it * 128 + g * 64;
        if (it < nit - 1) {
            FBODY(kbase, 0)
        } else {
            FBODY(kbase, 1)                 // diagonal 128 keys: both groups masked
        }
    }

    // ---- cross-group reduction: [vec][256 lanes][4] layout, 16B lane stride ----
    __syncthreads();                        // last FBODY reads done; LDS reusable
    if (g == 1) {
        float* dst = Red + (size_t)(w * 64 + lane) * 4;
#pragma unroll
        for (int mt = 0; mt < 2; ++mt)
#pragma unroll
            for (int nt = 0; nt < 4; ++nt)
                *(f32x4*)(dst + (mt * 4 + nt) * 1024) = accO[mt][nt];
        *(f32x4*)(dst + 8 * 1024) = lacc[0];
        *(f32x4*)(dst + 9 * 1024) = lacc[1];
    }
    __syncthreads();
    if (g == 0) {
        const float* src = Red + (size_t)(w * 64 + lane) * 4;
#pragma unroll
        for (int mt = 0; mt < 2; ++mt)
#pragma unroll
            for (int nt = 0; nt < 4; ++nt)
                accO[mt][nt] += *(const f32x4*)(src + (mt * 4 + nt) * 1024);
        lacc[0] += *(const f32x4*)(src + 8 * 1024);
        lacc[1] += *(const f32x4*)(src + 9 * 1024);

        // epilogue: accO lane layout q = mt*16 + quad*4 + r
#pragma unroll
        for (int mt = 0; mt < 2; ++mt) {
            float inv[4];
#pragma unroll
            for (int r_ = 0; r_ < 4; ++r_) inv[r_] = 1.0f / lacc[mt][r_];
#pragma unroll
            for (int nt = 0; nt < 4; ++nt)
#pragma unroll
                for (int r_ = 0; r_ < 4; ++r_)
                    O[(size_t)(qrow0 + mt * 16 + quad * 4 + r_) * 1024 +
                      h * 64 + nt * 16 + l15] = f2bf(accO[mt][nt][r_] * inv[r_]);
        }
    }
}

extern "C" void kernel_launch(void* const* d_in, const int* in_sizes, int n_in,
                              void* d_out, int out_size, void* d_ws, size_t ws_size,
                              hipStream_t stream) {
    (void)in_sizes; (void)n_in; (void)out_size; (void)ws_size;
    const float* x  = (const float*)d_in[0];
    const float* wq = (const float*)d_in[1];
    const float* wk = (const float*)d_in[2];
    const float* wv = (const float*)d_in[3];
    const float* wo = (const float*)d_in[4];
    float* out = (float*)d_out;

    const size_t T = (size_t)4096 * 1024;
    const size_t W = (size_t)1024 * 1024;
    unsigned short* Q   = (unsigned short*)d_ws;
    unsigned short* K   = Q + T;
    unsigned short* Vt  = K + T;      // f16 [ch][token], ldc 4096
    unsigned short* xb  = Vt + T;
    unsigned short* AO  = xb;         // alias: xb dead after gemm_qkv, AO written by flash
    unsigned short* wqb = xb + T;
    unsigned short* wkb = wqb + W;
    unsigned short* wvb = wkb + W;
    unsigned short* wob = wvb + W;
    // ws use: 4*8MB + 4*2MB = 40MB

    cvt_all  <<<dim3(4096),   256, 0, stream>>>(x, wq, wk, wv, wo, xb, wqb, wkb, wvb, wob);
    gemm_qkv <<<dim3(32, 24), 256, 0, stream>>>(xb, wqb, wkb, wvb, Q, K, Vt);
    flash_attn<<<dim3(512),   512, 0, stream>>>(Q, K, Vt, AO);
    gemm_out <<<dim3(32, 8),  256, 0, stream>>>(AO, wob, out);
}